// Round 1
// baseline (671.051 us; speedup 1.0000x reference)
//
#include <hip/hip_runtime.h>
#include <math.h>

#define NG 128          // graphs
#define NPG 256         // nodes per graph
#define NN 32768        // total nodes
#define HDIM 256        // hidden
#define FIN 128         // input features

// ---------------- CSR build ----------------
__global__ void k_count(const int* __restrict__ dst, int* __restrict__ counts, int E) {
    int e = blockIdx.x * blockDim.x + threadIdx.x;
    if (e < E) atomicAdd(&counts[dst[e]], 1);
}

__global__ void k_scan(const int* __restrict__ counts, int* __restrict__ rowptr) {
    __shared__ int sums[1024];
    int tid = threadIdx.x;
    int base = tid * 32;
    int local[32];
    int s = 0;
#pragma unroll
    for (int j = 0; j < 32; j++) { local[j] = s; s += counts[base + j]; }
    sums[tid] = s;
    __syncthreads();
    for (int off = 1; off < 1024; off <<= 1) {
        int v = (tid >= off) ? sums[tid - off] : 0;
        __syncthreads();
        sums[tid] += v;
        __syncthreads();
    }
    int prev = (tid > 0) ? sums[tid - 1] : 0;
#pragma unroll
    for (int j = 0; j < 32; j++) rowptr[base + j] = prev + local[j];
    if (tid == 1023) rowptr[NN] = sums[1023];
}

__global__ void k_fill(const int* __restrict__ src, const int* __restrict__ dst,
                       const int* __restrict__ rowptr, int* __restrict__ cursor,
                       int* __restrict__ csr_src, int E) {
    int e = blockIdx.x * blockDim.x + threadIdx.x;
    if (e < E) {
        int d = dst[e];
        int p = atomicAdd(&cursor[d], 1);
        csr_src[rowptr[d] + p] = src[e];
    }
}

// deterministic within-node order: sort each segment by src value
__global__ void k_sort(const int* __restrict__ rowptr, int* __restrict__ csr) {
    int i = blockIdx.x * blockDim.x + threadIdx.x;
    if (i >= NN) return;
    int e0 = rowptr[i], e1 = rowptr[i + 1];
    for (int a = e0 + 1; a < e1; a++) {
        int key = csr[a];
        int b = a - 1;
        while (b >= e0 && csr[b] > key) { csr[b + 1] = csr[b]; b--; }
        csr[b + 1] = key;
    }
}

__global__ void k_init_mask(float* __restrict__ nmask) {
    int i = blockIdx.x * blockDim.x + threadIdx.x;
    if (i < NN) nmask[i] = 1.0f;
}

// ---------------- SGEMM: C[M x 256] = A[M x K] @ B[K x 256], f32 ----------------
#define BM 64
#define BN 64
#define BK 16
__global__ __launch_bounds__(256) void k_sgemm(const float* __restrict__ A,
                                               const float* __restrict__ B,
                                               float* __restrict__ C, int K) {
    const int N = HDIM;
    __shared__ float As[BK][BM];
    __shared__ float Bs[BK][BN];
    int tid = threadIdx.x;
    int tx = tid & 15, ty = tid >> 4;
    int row0 = blockIdx.y * BM, col0 = blockIdx.x * BN;
    float acc[4][4] = {};
    for (int kb = 0; kb < K; kb += BK) {
        {
            int l = tid * 4;
            int m = l >> 4, k = l & 15;
            float4 av = *reinterpret_cast<const float4*>(&A[(size_t)(row0 + m) * K + kb + k]);
            As[k + 0][m] = av.x; As[k + 1][m] = av.y; As[k + 2][m] = av.z; As[k + 3][m] = av.w;
        }
        {
            int l = tid * 4;
            int k = l >> 6, c = l & 63;
            *reinterpret_cast<float4*>(&Bs[k][c]) =
                *reinterpret_cast<const float4*>(&B[(size_t)(kb + k) * N + col0 + c]);
        }
        __syncthreads();
#pragma unroll
        for (int k = 0; k < BK; k++) {
            float4 a = *reinterpret_cast<float4*>(&As[k][ty * 4]);
            float4 b = *reinterpret_cast<float4*>(&Bs[k][tx * 4]);
            float av[4] = {a.x, a.y, a.z, a.w};
            float bv[4] = {b.x, b.y, b.z, b.w};
#pragma unroll
            for (int i = 0; i < 4; i++)
#pragma unroll
                for (int j = 0; j < 4; j++) acc[i][j] += av[i] * bv[j];
        }
        __syncthreads();
    }
#pragma unroll
    for (int i = 0; i < 4; i++) {
        float4 v = make_float4(acc[i][0], acc[i][1], acc[i][2], acc[i][3]);
        *reinterpret_cast<float4*>(&C[(size_t)(row0 + ty * 4 + i) * N + col0 + tx * 4]) = v;
    }
}

// ---------------- per-stage kernels ----------------
// dis[i] = nmask[i]>0 ? rsqrt(1 + #active incoming) : 0
__global__ void k_dis(const float* __restrict__ nmask, const int* __restrict__ rowptr,
                      const int* __restrict__ csr, float* __restrict__ dis) {
    int i = blockIdx.x * blockDim.x + threadIdx.x;
    if (i >= NN) return;
    if (nmask[i] <= 0.f) { dis[i] = 0.f; return; }
    int e0 = rowptr[i], e1 = rowptr[i + 1];
    int cnt = 1;
    for (int e = e0; e < e1; e++) cnt += (nmask[csr[e]] > 0.f) ? 1 : 0;
    dis[i] = rsqrtf((float)cnt);
}

// wave per node: out = relu(b + hW[i]*dis^2 + sum_active hW[src]*dis[src]*dis[i])
__global__ __launch_bounds__(256) void k_gcn_agg(const float* __restrict__ hW,
                                                 const float* __restrict__ dis,
                                                 const int* __restrict__ rowptr,
                                                 const int* __restrict__ csr,
                                                 const float* __restrict__ bias,
                                                 float* __restrict__ out) {
    int wid = (blockIdx.x * blockDim.x + threadIdx.x) >> 6;
    int lane = threadIdx.x & 63;
    if (wid >= NN) return;
    float di = dis[wid];
    float4 h = *reinterpret_cast<const float4*>(&hW[(size_t)wid * HDIM + lane * 4]);
    float self = di * di;
    float ax = h.x * self, ay = h.y * self, az = h.z * self, aw = h.w * self;
    if (di > 0.f) {
        int e0 = rowptr[wid], e1 = rowptr[wid + 1];
        for (int e = e0; e < e1; e++) {
            int s = csr[e];
            float ds = dis[s];
            if (ds > 0.f) {
                float w = ds * di;
                float4 hs = *reinterpret_cast<const float4*>(&hW[(size_t)s * HDIM + lane * 4]);
                ax += hs.x * w; ay += hs.y * w; az += hs.z * w; aw += hs.w * w;
            }
        }
    }
    float4 b = *reinterpret_cast<const float4*>(&bias[lane * 4]);
    float4 o;
    o.x = fmaxf(ax + b.x, 0.f);
    o.y = fmaxf(ay + b.y, 0.f);
    o.z = fmaxf(az + b.z, 0.f);
    o.w = fmaxf(aw + b.w, 0.f);
    *reinterpret_cast<float4*>(&out[(size_t)wid * HDIM + lane * 4]) = o;
}

// wave per node: r_rel = h . w_rel, r_root = h . w_root
__global__ __launch_bounds__(256) void k_dots(const float* __restrict__ h,
                                              const float* __restrict__ w_rel,
                                              const float* __restrict__ w_root,
                                              float* __restrict__ r_rel,
                                              float* __restrict__ r_root) {
    int wid = (blockIdx.x * blockDim.x + threadIdx.x) >> 6;
    int lane = threadIdx.x & 63;
    if (wid >= NN) return;
    float4 hv = *reinterpret_cast<const float4*>(&h[(size_t)wid * HDIM + lane * 4]);
    float4 wr = *reinterpret_cast<const float4*>(&w_rel[lane * 4]);
    float4 wo = *reinterpret_cast<const float4*>(&w_root[lane * 4]);
    float s1 = hv.x * wr.x + hv.y * wr.y + hv.z * wr.z + hv.w * wr.w;
    float s2 = hv.x * wo.x + hv.y * wo.y + hv.z * wo.z + hv.w * wo.w;
    for (int off = 32; off > 0; off >>= 1) {
        s1 += __shfl_down(s1, off);
        s2 += __shfl_down(s2, off);
    }
    if (lane == 0) { r_rel[wid] = s1; r_root[wid] = s2; }
}

__global__ void k_score(const float* __restrict__ nmask, const int* __restrict__ rowptr,
                        const int* __restrict__ csr, const float* __restrict__ r_rel,
                        const float* __restrict__ r_root, const float* __restrict__ b_rel,
                        float* __restrict__ score) {
    int i = blockIdx.x * blockDim.x + threadIdx.x;
    if (i >= NN) return;
    if (nmask[i] <= 0.f) { score[i] = -INFINITY; return; }
    float s = b_rel[0] + r_root[i];
    int e0 = rowptr[i], e1 = rowptr[i + 1];
    for (int e = e0; e < e1; e++) {
        int src = csr[e];
        if (nmask[src] > 0.f) s += r_rel[src];
    }
    score[i] = s;
}

// block per graph: stable top-k via rank counting; writes new nmask
__global__ __launch_bounds__(256) void k_topk(const float* __restrict__ score, int k,
                                              float* __restrict__ nmask) {
    __shared__ float sc[NPG];
    int g = blockIdx.x, tid = threadIdx.x;
    float my = score[g * NPG + tid];
    sc[tid] = my;
    __syncthreads();
    int cnt = 0;
    for (int j = 0; j < NPG; j++) {
        float v = sc[j];
        cnt += (v > my || (v == my && j < tid)) ? 1 : 0;
    }
    nmask[g * NPG + tid] = (cnt < k) ? 1.0f : 0.0f;
}

// x[i] = selected ? x[i]*tanh(score[i]) : 0
__global__ __launch_bounds__(256) void k_scale(float* __restrict__ h,
                                               const float* __restrict__ score,
                                               const float* __restrict__ nmask) {
    int wid = (blockIdx.x * blockDim.x + threadIdx.x) >> 6;
    int lane = threadIdx.x & 63;
    if (wid >= NN) return;
    float4* p = reinterpret_cast<float4*>(&h[(size_t)wid * HDIM + lane * 4]);
    float4 v = *p;
    if (nmask[wid] > 0.f) {
        float t = tanhf(score[wid]);
        v.x *= t; v.y *= t; v.z *= t; v.w *= t;
    } else {
        v.x = v.y = v.z = v.w = 0.f;
    }
    *p = v;
}

// block per graph, thread per feature: z += [s/k, max, s]
__global__ __launch_bounds__(256) void k_readout(const float* __restrict__ h,
                                                 const float* __restrict__ nmask, float invk,
                                                 float* __restrict__ z) {
    int g = blockIdx.x, f = threadIdx.x;
    float s = 0.f, mx = -INFINITY;
    for (int n = 0; n < NPG; n++) {
        if (nmask[g * NPG + n] > 0.f) {
            float v = h[(size_t)(g * NPG + n) * HDIM + f];
            s += v;
            mx = fmaxf(mx, v);
        }
    }
    z[g * 768 + f] += s * invk;
    z[g * 768 + 256 + f] += mx;
    z[g * 768 + 512 + f] += s;
}

// ---------------- final MLP + log_softmax, block per graph ----------------
__global__ __launch_bounds__(256) void k_mlp(const float* __restrict__ z,
                                             const float* __restrict__ W1, const float* __restrict__ b1,
                                             const float* __restrict__ W2, const float* __restrict__ b2,
                                             const float* __restrict__ W3, const float* __restrict__ b3,
                                             float* __restrict__ out) {
    __shared__ float zb[768];
    __shared__ float t1[256];
    __shared__ float t2[128];
    __shared__ float t3[10];
    __shared__ float lse;
    int g = blockIdx.x, tid = threadIdx.x;
    zb[tid] = z[g * 768 + tid];
    zb[tid + 256] = z[g * 768 + 256 + tid];
    zb[tid + 512] = z[g * 768 + 512 + tid];
    __syncthreads();
    {
        float s = b1[tid];
        for (int i = 0; i < 768; i++) s += zb[i] * W1[(size_t)i * 256 + tid];
        t1[tid] = fmaxf(s, 0.f);
    }
    __syncthreads();
    if (tid < 128) {
        float s = b2[tid];
        for (int i = 0; i < 256; i++) s += t1[i] * W2[(size_t)i * 128 + tid];
        t2[tid] = fmaxf(s, 0.f);
    }
    __syncthreads();
    if (tid < 10) {
        float s = b3[tid];
        for (int i = 0; i < 128; i++) s += t2[i] * W3[(size_t)i * 10 + tid];
        t3[tid] = s;
    }
    __syncthreads();
    if (tid == 0) {
        float m = t3[0];
        for (int c = 1; c < 10; c++) m = fmaxf(m, t3[c]);
        float se = 0.f;
        for (int c = 0; c < 10; c++) se += expf(t3[c] - m);
        lse = m + logf(se);
    }
    __syncthreads();
    if (tid < 10) out[g * 10 + tid] = t3[tid] - lse;
}

// ---------------- launcher ----------------
extern "C" void kernel_launch(void* const* d_in, const int* in_sizes, int n_in,
                              void* d_out, int out_size, void* d_ws, size_t ws_size,
                              hipStream_t stream) {
    const float* x        = (const float*)d_in[0];
    const int*   ei       = (const int*)d_in[1];
    const float* conv1_W  = (const float*)d_in[3];
    const float* conv1_b  = (const float*)d_in[4];
    const float* conv2_W  = (const float*)d_in[5];
    const float* conv2_b  = (const float*)d_in[6];
    const float* conv3_W  = (const float*)d_in[7];
    const float* conv3_b  = (const float*)d_in[8];
    const float* p1_relW  = (const float*)d_in[9];
    const float* p1_relb  = (const float*)d_in[10];
    const float* p1_rootW = (const float*)d_in[11];
    const float* p2_relW  = (const float*)d_in[12];
    const float* p2_relb  = (const float*)d_in[13];
    const float* p2_rootW = (const float*)d_in[14];
    const float* fc1_W    = (const float*)d_in[15];
    const float* fc1_b    = (const float*)d_in[16];
    const float* fc2_W    = (const float*)d_in[17];
    const float* fc2_b    = (const float*)d_in[18];
    const float* fc3_W    = (const float*)d_in[19];
    const float* fc3_b    = (const float*)d_in[20];
    float* out = (float*)d_out;

    const int E = in_sizes[1] / 2;
    const int* e_src = ei;
    const int* e_dst = ei + E;

    // workspace layout
    char* base = (char*)d_ws;
    size_t off = 0;
    auto alloc = [&](size_t bytes) { size_t o = off; off = (off + bytes + 255) & ~(size_t)255; return o; };
    float* hW     = (float*)(base + alloc((size_t)NN * HDIM * 4));
    float* hcur   = (float*)(base + alloc((size_t)NN * HDIM * 4));
    float* dis    = (float*)(base + alloc(NN * 4));
    float* r_rel  = (float*)(base + alloc(NN * 4));
    float* r_root = (float*)(base + alloc(NN * 4));
    float* score  = (float*)(base + alloc(NN * 4));
    float* nmask  = (float*)(base + alloc(NN * 4));
    int*   rowptr = (int*)(base + alloc((NN + 1) * 4));
    int*   counts = (int*)(base + alloc(NN * 4));
    int*   cursor = (int*)(base + alloc(NN * 4));
    int*   csr    = (int*)(base + alloc((size_t)E * 4));
    float* z      = (float*)(base + alloc((size_t)NG * 768 * 4));

    // zero what we accumulate into
    hipMemsetAsync(counts, 0, NN * 4, stream);
    hipMemsetAsync(cursor, 0, NN * 4, stream);
    hipMemsetAsync(z, 0, (size_t)NG * 768 * 4, stream);

    // CSR build (deterministic after sort-by-src)
    int eblocks = (E + 255) / 256;
    k_count<<<eblocks, 256, 0, stream>>>(e_dst, counts, E);
    k_scan<<<1, 1024, 0, stream>>>(counts, rowptr);
    k_fill<<<eblocks, 256, 0, stream>>>(e_src, e_dst, rowptr, cursor, csr, E);
    k_sort<<<NN / 256, 256, 0, stream>>>(rowptr, csr);
    k_init_mask<<<NN / 256, 256, 0, stream>>>(nmask);

    const int nodeBlocks = NN / 256;          // thread per node
    const int waveBlocks = NN * 64 / 256;     // wave per node

    struct Stage {
        const float* X; int K;
        const float* W; const float* b;
        const float* wrel; const float* brel; const float* wroot;
        int kpool;
    };
    Stage stages[3] = {
        { x,    FIN,  conv1_W, conv1_b, p1_relW, p1_relb, p1_rootW, 128 },
        { hcur, HDIM, conv2_W, conv2_b, p2_relW, p2_relb, p2_rootW, 64  },
        { hcur, HDIM, conv3_W, conv3_b, p2_relW, p2_relb, p2_rootW, 32  },
    };

    for (int t = 0; t < 3; t++) {
        Stage& st = stages[t];
        dim3 ggrid(HDIM / BN, NN / BM);
        k_sgemm<<<ggrid, 256, 0, stream>>>(st.X, st.W, hW, st.K);
        k_dis<<<nodeBlocks, 256, 0, stream>>>(nmask, rowptr, csr, dis);
        k_gcn_agg<<<waveBlocks, 256, 0, stream>>>(hW, dis, rowptr, csr, st.b, hcur);
        k_dots<<<waveBlocks, 256, 0, stream>>>(hcur, st.wrel, st.wroot, r_rel, r_root);
        k_score<<<nodeBlocks, 256, 0, stream>>>(nmask, rowptr, csr, r_rel, r_root, st.brel, score);
        k_topk<<<NG, 256, 0, stream>>>(score, st.kpool, nmask);
        k_scale<<<waveBlocks, 256, 0, stream>>>(hcur, score, nmask);
        k_readout<<<NG, 256, 0, stream>>>(hcur, nmask, 1.0f / (float)st.kpool, z);
    }

    k_mlp<<<NG, 256, 0, stream>>>(z, fc1_W, fc1_b, fc2_W, fc2_b, fc3_W, fc3_b, out);
}

// Round 2
// 514.157 us; speedup vs baseline: 1.3051x; 1.3051x over previous
//
#include <hip/hip_runtime.h>
#include <math.h>

#define NG 128          // graphs
#define NPG 256         // nodes per graph
#define NN 32768        // total nodes
#define HDIM 256        // hidden
#define FIN 128         // input features

// ---------------- CSR build ----------------
__global__ void k_count(const int* __restrict__ dst, int* __restrict__ counts, int E) {
    int e = blockIdx.x * blockDim.x + threadIdx.x;
    if (e < E) atomicAdd(&counts[dst[e]], 1);
}

__global__ void k_scan(const int* __restrict__ counts, int* __restrict__ rowptr) {
    __shared__ int sums[1024];
    int tid = threadIdx.x;
    int base = tid * 32;
    int local[32];
    int s = 0;
#pragma unroll
    for (int j = 0; j < 32; j++) { local[j] = s; s += counts[base + j]; }
    sums[tid] = s;
    __syncthreads();
    for (int off = 1; off < 1024; off <<= 1) {
        int v = (tid >= off) ? sums[tid - off] : 0;
        __syncthreads();
        sums[tid] += v;
        __syncthreads();
    }
    int prev = (tid > 0) ? sums[tid - 1] : 0;
#pragma unroll
    for (int j = 0; j < 32; j++) rowptr[base + j] = prev + local[j];
    if (tid == 1023) rowptr[NN] = sums[1023];
}

__global__ void k_fill(const int* __restrict__ src, const int* __restrict__ dst,
                       const int* __restrict__ rowptr, int* __restrict__ cursor,
                       int* __restrict__ csr_src, int E) {
    int e = blockIdx.x * blockDim.x + threadIdx.x;
    if (e < E) {
        int d = dst[e];
        int p = atomicAdd(&cursor[d], 1);
        csr_src[rowptr[d] + p] = src[e];
    }
}

// deterministic canonical order: wave-parallel rank sort of each node's segment by src value
__global__ __launch_bounds__(256) void k_sortw(const int* __restrict__ rowptr, int* __restrict__ csr) {
    int wid = (blockIdx.x * blockDim.x + threadIdx.x) >> 6;
    int lane = threadIdx.x & 63;
    if (wid >= NN) return;
    int e0 = rowptr[wid];
    int d = rowptr[wid + 1] - e0;
    if (d <= 1) return;
    if (d <= 64) {
        int key = (lane < d) ? csr[e0 + lane] : 0x7fffffff;
        int rank = 0;
        for (int j = 0; j < d; j++) {
            int kj = __shfl(key, j);
            rank += (kj < key || (kj == key && j < lane)) ? 1 : 0;
        }
        if (lane < d) csr[e0 + rank] = key;
    } else if (lane == 0) {
        for (int a = e0 + 1; a < e0 + d; a++) {
            int key = csr[a];
            int b = a - 1;
            while (b >= e0 && csr[b] > key) { csr[b + 1] = csr[b]; b--; }
            csr[b + 1] = key;
        }
    }
}

__global__ void k_init_mask(float* __restrict__ nmask) {
    int i = blockIdx.x * blockDim.x + threadIdx.x;
    if (i < NN) nmask[i] = 1.0f;
}

// ---------------- SGEMM: C[list[m] x 256] = A[list[m] x K] @ B[K x 256], f32 ----------------
#define BM 64
#define BN 64
#define BK 16
__global__ __launch_bounds__(256) void k_sgemm(const float* __restrict__ A,
                                               const float* __restrict__ B,
                                               float* __restrict__ C, int K,
                                               const int* __restrict__ list) {
    const int N = HDIM;
    __shared__ float As[BK][BM];
    __shared__ float Bs[BK][BN];
    int tid = threadIdx.x;
    int tx = tid & 15, ty = tid >> 4;
    int row0 = blockIdx.y * BM, col0 = blockIdx.x * BN;
    // hoisted per-thread row indirection
    int lm = tid >> 2;                       // A-load row within tile
    int arow = list ? list[row0 + lm] : (row0 + lm);
    int crow[4];
#pragma unroll
    for (int i = 0; i < 4; i++) {
        int r = row0 + ty * 4 + i;
        crow[i] = list ? list[r] : r;
    }
    float acc[4][4] = {};
    for (int kb = 0; kb < K; kb += BK) {
        {
            int k = (tid & 3) * 4;
            float4 av = *reinterpret_cast<const float4*>(&A[(size_t)arow * K + kb + k]);
            As[k + 0][lm] = av.x; As[k + 1][lm] = av.y; As[k + 2][lm] = av.z; As[k + 3][lm] = av.w;
        }
        {
            int l = tid * 4;
            int k = l >> 6, c = l & 63;
            *reinterpret_cast<float4*>(&Bs[k][c]) =
                *reinterpret_cast<const float4*>(&B[(size_t)(kb + k) * N + col0 + c]);
        }
        __syncthreads();
#pragma unroll
        for (int k = 0; k < BK; k++) {
            float4 a = *reinterpret_cast<float4*>(&As[k][ty * 4]);
            float4 b = *reinterpret_cast<float4*>(&Bs[k][tx * 4]);
            float av[4] = {a.x, a.y, a.z, a.w};
            float bv[4] = {b.x, b.y, b.z, b.w};
#pragma unroll
            for (int i = 0; i < 4; i++)
#pragma unroll
                for (int j = 0; j < 4; j++) acc[i][j] += av[i] * bv[j];
        }
        __syncthreads();
    }
#pragma unroll
    for (int i = 0; i < 4; i++) {
        float4 v = make_float4(acc[i][0], acc[i][1], acc[i][2], acc[i][3]);
        *reinterpret_cast<float4*>(&C[(size_t)crow[i] * N + col0 + tx * 4]) = v;
    }
}

// ---------------- per-stage kernels ----------------
// dis[i] = nmask[i]>0 ? rsqrt(1 + #active incoming) : 0
__global__ void k_dis(const float* __restrict__ nmask, const int* __restrict__ rowptr,
                      const int* __restrict__ csr, float* __restrict__ dis) {
    int i = blockIdx.x * blockDim.x + threadIdx.x;
    if (i >= NN) return;
    if (nmask[i] <= 0.f) { dis[i] = 0.f; return; }
    int e0 = rowptr[i], e1 = rowptr[i + 1];
    int cnt = 1;
    for (int e = e0; e < e1; e++) cnt += (nmask[csr[e]] > 0.f) ? 1 : 0;
    dis[i] = rsqrtf((float)cnt);
}

// wave per ACTIVE node: out = relu(b + hW[i]*dis^2 + sum hW[src]*dis[src]*dis[i])
// fused epilogue: r_rel = out . w_rel, r_root = out . w_root
__global__ __launch_bounds__(256) void k_gcn_agg(const float* __restrict__ hW,
                                                 const float* __restrict__ dis,
                                                 const int* __restrict__ rowptr,
                                                 const int* __restrict__ csr,
                                                 const float* __restrict__ bias,
                                                 const int* __restrict__ list, int nact,
                                                 const float* __restrict__ w_rel,
                                                 const float* __restrict__ w_root,
                                                 float* __restrict__ out,
                                                 float* __restrict__ r_rel,
                                                 float* __restrict__ r_root) {
    int idx = (blockIdx.x * blockDim.x + threadIdx.x) >> 6;
    int lane = threadIdx.x & 63;
    if (idx >= nact) return;
    int wid = list ? list[idx] : idx;
    float di = dis[wid];
    float4 h = *reinterpret_cast<const float4*>(&hW[(size_t)wid * HDIM + lane * 4]);
    float self = di * di;
    float ax = h.x * self, ay = h.y * self, az = h.z * self, aw = h.w * self;
    if (di > 0.f) {
        int e0 = rowptr[wid], e1 = rowptr[wid + 1];
        for (int e = e0; e < e1; e++) {
            int s = csr[e];
            float ds = dis[s];
            if (ds > 0.f) {
                float w = ds * di;
                float4 hs = *reinterpret_cast<const float4*>(&hW[(size_t)s * HDIM + lane * 4]);
                ax += hs.x * w; ay += hs.y * w; az += hs.z * w; aw += hs.w * w;
            }
        }
    }
    float4 b = *reinterpret_cast<const float4*>(&bias[lane * 4]);
    float4 o;
    o.x = fmaxf(ax + b.x, 0.f);
    o.y = fmaxf(ay + b.y, 0.f);
    o.z = fmaxf(az + b.z, 0.f);
    o.w = fmaxf(aw + b.w, 0.f);
    *reinterpret_cast<float4*>(&out[(size_t)wid * HDIM + lane * 4]) = o;
    // fused score dot products
    float4 wr = *reinterpret_cast<const float4*>(&w_rel[lane * 4]);
    float4 wo = *reinterpret_cast<const float4*>(&w_root[lane * 4]);
    float s1 = o.x * wr.x + o.y * wr.y + o.z * wr.z + o.w * wr.w;
    float s2 = o.x * wo.x + o.y * wo.y + o.z * wo.z + o.w * wo.w;
    for (int off = 32; off > 0; off >>= 1) {
        s1 += __shfl_down(s1, off);
        s2 += __shfl_down(s2, off);
    }
    if (lane == 0) { r_rel[wid] = s1; r_root[wid] = s2; }
}

__global__ void k_score(const float* __restrict__ nmask, const int* __restrict__ rowptr,
                        const int* __restrict__ csr, const float* __restrict__ r_rel,
                        const float* __restrict__ r_root, const float* __restrict__ b_rel,
                        float* __restrict__ score) {
    int i = blockIdx.x * blockDim.x + threadIdx.x;
    if (i >= NN) return;
    if (nmask[i] <= 0.f) { score[i] = -INFINITY; return; }
    float s = b_rel[0] + r_root[i];
    int e0 = rowptr[i], e1 = rowptr[i + 1];
    for (int e = e0; e < e1; e++) {
        int src = csr[e];
        if (nmask[src] > 0.f) s += r_rel[src];
    }
    score[i] = s;
}

// block per graph: stable top-k via rank counting; writes new nmask
__global__ __launch_bounds__(256) void k_topk(const float* __restrict__ score, int k,
                                              float* __restrict__ nmask) {
    __shared__ float sc[NPG];
    int g = blockIdx.x, tid = threadIdx.x;
    float my = score[g * NPG + tid];
    sc[tid] = my;
    __syncthreads();
    int cnt = 0;
    for (int j = 0; j < NPG; j++) {
        float v = sc[j];
        cnt += (v > my || (v == my && j < tid)) ? 1 : 0;
    }
    nmask[g * NPG + tid] = (cnt < k) ? 1.0f : 0.0f;
}

// block per graph: deterministic active-node list (ascending node index)
__global__ __launch_bounds__(256) void k_build_list(const float* __restrict__ nmask, int k,
                                                    int* __restrict__ list) {
    __shared__ int pref[NPG];
    int g = blockIdx.x, tid = threadIdx.x;
    int a = (nmask[g * NPG + tid] > 0.f) ? 1 : 0;
    pref[tid] = a;
    __syncthreads();
    for (int off = 1; off < NPG; off <<= 1) {
        int v = (tid >= off) ? pref[tid - off] : 0;
        __syncthreads();
        pref[tid] += v;
        __syncthreads();
    }
    if (a) list[g * k + pref[tid] - 1] = g * NPG + tid;
}

// block per graph: fused x *= tanh(score)*mask (active rows only) + readout accumulate
__global__ __launch_bounds__(256) void k_poolout(float* __restrict__ h,
                                                 const float* __restrict__ score,
                                                 const float* __restrict__ nmask, float invk,
                                                 float* __restrict__ z) {
    __shared__ float tv[NPG];
    int g = blockIdx.x, f = threadIdx.x;
    {
        int node = g * NPG + f;
        tv[f] = (nmask[node] > 0.f) ? tanhf(score[node]) : 0.f;
    }
    __syncthreads();
    float s = 0.f, mx = -INFINITY;
    for (int n = 0; n < NPG; n++) {
        float t = tv[n];
        if (t != 0.f || nmask[g * NPG + n] > 0.f) {   // active (t may be exactly 0)
            size_t p = (size_t)(g * NPG + n) * HDIM + f;
            float v = h[p] * t;
            h[p] = v;
            s += v;
            mx = fmaxf(mx, v);
        }
    }
    z[g * 768 + f] += s * invk;
    z[g * 768 + 256 + f] += mx;
    z[g * 768 + 512 + f] += s;
}

// ---------------- final MLP + log_softmax, block per graph ----------------
__global__ __launch_bounds__(256) void k_mlp(const float* __restrict__ z,
                                             const float* __restrict__ W1, const float* __restrict__ b1,
                                             const float* __restrict__ W2, const float* __restrict__ b2,
                                             const float* __restrict__ W3, const float* __restrict__ b3,
                                             float* __restrict__ out) {
    __shared__ float zb[768];
    __shared__ float t1[256];
    __shared__ float t2[128];
    __shared__ float t3[10];
    __shared__ float lse;
    int g = blockIdx.x, tid = threadIdx.x;
    zb[tid] = z[g * 768 + tid];
    zb[tid + 256] = z[g * 768 + 256 + tid];
    zb[tid + 512] = z[g * 768 + 512 + tid];
    __syncthreads();
    {
        float s = b1[tid];
        for (int i = 0; i < 768; i++) s += zb[i] * W1[(size_t)i * 256 + tid];
        t1[tid] = fmaxf(s, 0.f);
    }
    __syncthreads();
    if (tid < 128) {
        float s = b2[tid];
        for (int i = 0; i < 256; i++) s += t1[i] * W2[(size_t)i * 128 + tid];
        t2[tid] = fmaxf(s, 0.f);
    }
    __syncthreads();
    if (tid < 10) {
        float s = b3[tid];
        for (int i = 0; i < 128; i++) s += t2[i] * W3[(size_t)i * 10 + tid];
        t3[tid] = s;
    }
    __syncthreads();
    if (tid == 0) {
        float m = t3[0];
        for (int c = 1; c < 10; c++) m = fmaxf(m, t3[c]);
        float se = 0.f;
        for (int c = 0; c < 10; c++) se += expf(t3[c] - m);
        lse = m + logf(se);
    }
    __syncthreads();
    if (tid < 10) out[g * 10 + tid] = t3[tid] - lse;
}

// ---------------- launcher ----------------
extern "C" void kernel_launch(void* const* d_in, const int* in_sizes, int n_in,
                              void* d_out, int out_size, void* d_ws, size_t ws_size,
                              hipStream_t stream) {
    const float* x        = (const float*)d_in[0];
    const int*   ei       = (const int*)d_in[1];
    const float* conv1_W  = (const float*)d_in[3];
    const float* conv1_b  = (const float*)d_in[4];
    const float* conv2_W  = (const float*)d_in[5];
    const float* conv2_b  = (const float*)d_in[6];
    const float* conv3_W  = (const float*)d_in[7];
    const float* conv3_b  = (const float*)d_in[8];
    const float* p1_relW  = (const float*)d_in[9];
    const float* p1_relb  = (const float*)d_in[10];
    const float* p1_rootW = (const float*)d_in[11];
    const float* p2_relW  = (const float*)d_in[12];
    const float* p2_relb  = (const float*)d_in[13];
    const float* p2_rootW = (const float*)d_in[14];
    const float* fc1_W    = (const float*)d_in[15];
    const float* fc1_b    = (const float*)d_in[16];
    const float* fc2_W    = (const float*)d_in[17];
    const float* fc2_b    = (const float*)d_in[18];
    const float* fc3_W    = (const float*)d_in[19];
    const float* fc3_b    = (const float*)d_in[20];
    float* out = (float*)d_out;

    const int E = in_sizes[1] / 2;
    const int* e_src = ei;
    const int* e_dst = ei + E;

    // workspace layout
    char* base = (char*)d_ws;
    size_t off = 0;
    auto alloc = [&](size_t bytes) { size_t o = off; off = (off + bytes + 255) & ~(size_t)255; return o; };
    float* hW     = (float*)(base + alloc((size_t)NN * HDIM * 4));
    float* hcur   = (float*)(base + alloc((size_t)NN * HDIM * 4));
    float* dis    = (float*)(base + alloc(NN * 4));
    float* r_rel  = (float*)(base + alloc(NN * 4));
    float* r_root = (float*)(base + alloc(NN * 4));
    float* score  = (float*)(base + alloc(NN * 4));
    float* nmask  = (float*)(base + alloc(NN * 4));
    int*   rowptr = (int*)(base + alloc((NN + 1) * 4));
    int*   counts = (int*)(base + alloc(NN * 4));
    int*   cursor = (int*)(base + alloc(NN * 4));
    int*   csr    = (int*)(base + alloc((size_t)E * 4));
    float* z      = (float*)(base + alloc((size_t)NG * 768 * 4));
    int*   list1  = (int*)(base + alloc((size_t)NG * 128 * 4));
    int*   list2  = (int*)(base + alloc((size_t)NG * 64 * 4));

    hipMemsetAsync(counts, 0, NN * 4, stream);
    hipMemsetAsync(cursor, 0, NN * 4, stream);
    hipMemsetAsync(z, 0, (size_t)NG * 768 * 4, stream);

    // CSR build (canonical sorted-by-src order => deterministic)
    int eblocks = (E + 255) / 256;
    k_count<<<eblocks, 256, 0, stream>>>(e_dst, counts, E);
    k_scan<<<1, 1024, 0, stream>>>(counts, rowptr);
    k_fill<<<eblocks, 256, 0, stream>>>(e_src, e_dst, rowptr, cursor, csr, E);
    k_sortw<<<NN * 64 / 256, 256, 0, stream>>>(rowptr, csr);
    k_init_mask<<<NN / 256, 256, 0, stream>>>(nmask);

    const int nodeBlocks = NN / 256;

    struct Stage {
        const float* X; int K;
        const float* W; const float* b;
        const float* wrel; const float* brel; const float* wroot;
        int kpool;
        const int* list; int nact;     // active rows for this stage's conv
        int* outlist;                  // list to build after this stage's pool
    };
    Stage stages[3] = {
        { x,    FIN,  conv1_W, conv1_b, p1_relW, p1_relb, p1_rootW, 128, nullptr, NN,    list1 },
        { hcur, HDIM, conv2_W, conv2_b, p2_relW, p2_relb, p2_rootW, 64,  list1,  16384, list2 },
        { hcur, HDIM, conv3_W, conv3_b, p2_relW, p2_relb, p2_rootW, 32,  list2,  8192,  nullptr },
    };

    for (int t = 0; t < 3; t++) {
        Stage& st = stages[t];
        dim3 ggrid(HDIM / BN, st.nact / BM);
        k_sgemm<<<ggrid, 256, 0, stream>>>(st.X, st.W, hW, st.K, st.list);
        k_dis<<<nodeBlocks, 256, 0, stream>>>(nmask, rowptr, csr, dis);
        k_gcn_agg<<<st.nact * 64 / 256, 256, 0, stream>>>(hW, dis, rowptr, csr, st.b,
                                                          st.list, st.nact, st.wrel, st.wroot,
                                                          hcur, r_rel, r_root);
        k_score<<<nodeBlocks, 256, 0, stream>>>(nmask, rowptr, csr, r_rel, r_root, st.brel, score);
        k_topk<<<NG, 256, 0, stream>>>(score, st.kpool, nmask);
        if (st.outlist) k_build_list<<<NG, 256, 0, stream>>>(nmask, st.kpool, st.outlist);
        k_poolout<<<NG, 256, 0, stream>>>(hcur, score, nmask, 1.0f / (float)st.kpool, z);
    }

    k_mlp<<<NG, 256, 0, stream>>>(z, fc1_W, fc1_b, fc2_W, fc2_b, fc3_W, fc3_b, out);
}

// Round 3
// 469.378 us; speedup vs baseline: 1.4297x; 1.0954x over previous
//
#include <hip/hip_runtime.h>
#include <math.h>

#define NG 128          // graphs
#define NPG 256         // nodes per graph
#define NN 32768        // total nodes
#define HDIM 256        // hidden
#define FIN 128         // input features

// ---------------- CSR build ----------------
__global__ void k_count(const int* __restrict__ dst, int* __restrict__ counts, int E) {
    int e = blockIdx.x * blockDim.x + threadIdx.x;
    if (e < E) atomicAdd(&counts[dst[e]], 1);
}

__global__ void k_scan(const int* __restrict__ counts, int* __restrict__ rowptr) {
    __shared__ int sums[1024];
    int tid = threadIdx.x;
    int base = tid * 32;
    int local[32];
    int s = 0;
#pragma unroll
    for (int j = 0; j < 32; j++) { local[j] = s; s += counts[base + j]; }
    sums[tid] = s;
    __syncthreads();
    for (int off = 1; off < 1024; off <<= 1) {
        int v = (tid >= off) ? sums[tid - off] : 0;
        __syncthreads();
        sums[tid] += v;
        __syncthreads();
    }
    int prev = (tid > 0) ? sums[tid - 1] : 0;
#pragma unroll
    for (int j = 0; j < 32; j++) rowptr[base + j] = prev + local[j];
    if (tid == 1023) rowptr[NN] = sums[1023];
}

__global__ void k_fill(const int* __restrict__ src, const int* __restrict__ dst,
                       const int* __restrict__ rowptr, int* __restrict__ cursor,
                       int* __restrict__ csr_src, int E) {
    int e = blockIdx.x * blockDim.x + threadIdx.x;
    if (e < E) {
        int d = dst[e];
        int p = atomicAdd(&cursor[d], 1);
        csr_src[rowptr[d] + p] = src[e];
    }
}

// deterministic canonical order: wave-parallel rank sort of each node's segment by src value
__global__ __launch_bounds__(256) void k_sortw(const int* __restrict__ rowptr, int* __restrict__ csr) {
    int wid = (blockIdx.x * blockDim.x + threadIdx.x) >> 6;
    int lane = threadIdx.x & 63;
    if (wid >= NN) return;
    int e0 = rowptr[wid];
    int d = rowptr[wid + 1] - e0;
    if (d <= 1) return;
    if (d <= 64) {
        int key = (lane < d) ? csr[e0 + lane] : 0x7fffffff;
        int rank = 0;
        for (int j = 0; j < d; j++) {
            int kj = __shfl(key, j);
            rank += (kj < key || (kj == key && j < lane)) ? 1 : 0;
        }
        if (lane < d) csr[e0 + rank] = key;
    } else if (lane == 0) {
        for (int a = e0 + 1; a < e0 + d; a++) {
            int key = csr[a];
            int b = a - 1;
            while (b >= e0 && csr[b] > key) { csr[b + 1] = csr[b]; b--; }
            csr[b + 1] = key;
        }
    }
}

__global__ void k_init_mask(float* __restrict__ nmask) {
    int i = blockIdx.x * blockDim.x + threadIdx.x;
    if (i < NN) nmask[i] = 1.0f;
}

// ---------------- SGEMM: C[list[m] x 256] = A[list[m] x K] @ B[K x 256], f32 ----------------
// optional fused epilogue: C = relu(acc + brelu[col])
#define BM 64
#define BN 64
#define BK 16
__global__ __launch_bounds__(256) void k_sgemm(const float* __restrict__ A,
                                               const float* __restrict__ B,
                                               float* __restrict__ C, int K,
                                               const int* __restrict__ list,
                                               const float* __restrict__ brelu) {
    const int N = HDIM;
    __shared__ float As[BK][BM];
    __shared__ float Bs[BK][BN];
    int tid = threadIdx.x;
    int tx = tid & 15, ty = tid >> 4;
    int row0 = blockIdx.y * BM, col0 = blockIdx.x * BN;
    int lm = tid >> 2;
    int arow = list ? list[row0 + lm] : (row0 + lm);
    int crow[4];
#pragma unroll
    for (int i = 0; i < 4; i++) {
        int r = row0 + ty * 4 + i;
        crow[i] = list ? list[r] : r;
    }
    float acc[4][4] = {};
    for (int kb = 0; kb < K; kb += BK) {
        {
            int k = (tid & 3) * 4;
            float4 av = *reinterpret_cast<const float4*>(&A[(size_t)arow * K + kb + k]);
            As[k + 0][lm] = av.x; As[k + 1][lm] = av.y; As[k + 2][lm] = av.z; As[k + 3][lm] = av.w;
        }
        {
            int l = tid * 4;
            int k = l >> 6, c = l & 63;
            *reinterpret_cast<float4*>(&Bs[k][c]) =
                *reinterpret_cast<const float4*>(&B[(size_t)(kb + k) * N + col0 + c]);
        }
        __syncthreads();
#pragma unroll
        for (int k = 0; k < BK; k++) {
            float4 a = *reinterpret_cast<float4*>(&As[k][ty * 4]);
            float4 b = *reinterpret_cast<float4*>(&Bs[k][tx * 4]);
            float av[4] = {a.x, a.y, a.z, a.w};
            float bv[4] = {b.x, b.y, b.z, b.w};
#pragma unroll
            for (int i = 0; i < 4; i++)
#pragma unroll
                for (int j = 0; j < 4; j++) acc[i][j] += av[i] * bv[j];
        }
        __syncthreads();
    }
    float4 bb = make_float4(0.f, 0.f, 0.f, 0.f);
    if (brelu) bb = *reinterpret_cast<const float4*>(&brelu[col0 + tx * 4]);
#pragma unroll
    for (int i = 0; i < 4; i++) {
        float4 v = make_float4(acc[i][0], acc[i][1], acc[i][2], acc[i][3]);
        if (brelu) {
            v.x = fmaxf(v.x + bb.x, 0.f);
            v.y = fmaxf(v.y + bb.y, 0.f);
            v.z = fmaxf(v.z + bb.z, 0.f);
            v.w = fmaxf(v.w + bb.w, 0.f);
        }
        *reinterpret_cast<float4*>(&C[(size_t)crow[i] * N + col0 + tx * 4]) = v;
    }
}

// ---------------- per-stage kernels ----------------
// dis[i] = nmask[i]>0 ? rsqrt(1 + #active incoming) : 0
__global__ void k_dis(const float* __restrict__ nmask, const int* __restrict__ rowptr,
                      const int* __restrict__ csr, float* __restrict__ dis) {
    int i = blockIdx.x * blockDim.x + threadIdx.x;
    if (i >= NN) return;
    if (nmask[i] <= 0.f) { dis[i] = 0.f; return; }
    int e0 = rowptr[i], e1 = rowptr[i + 1];
    int cnt = 1;
    for (int e = e0; e < e1; e++) cnt += (nmask[csr[e]] > 0.f) ? 1 : 0;
    dis[i] = rsqrtf((float)cnt);
}

// XCD-locality swizzle: all blocks of one graph land on one XCD's L2.
// bpg = blocks per graph; requires gridDim.x == NG*bpg, NG%8==0.
__device__ __forceinline__ int swz_block(int bid, int bpg) {
    int xcd = bid & 7, r = bid >> 3;
    int graph = xcd * (NG / 8) + r / bpg;
    int sub = r - (r / bpg) * bpg;
    return graph * bpg + sub;
}

// stage 1 only (all nodes active): xa = D^{-1/2}(A+I)D^{-1/2} x  (x is FIN wide)
__global__ __launch_bounds__(256) void k_agg_x(const float* __restrict__ x,
                                               const float* __restrict__ dis,
                                               const int* __restrict__ rowptr,
                                               const int* __restrict__ csr,
                                               float* __restrict__ xa) {
    int blk = swz_block(blockIdx.x, NN / (NG * 4));
    int wid = blk * 4 + (threadIdx.x >> 6);
    int lane = threadIdx.x & 63;
    float di = dis[wid];
    float2 h = *reinterpret_cast<const float2*>(&x[(size_t)wid * FIN + lane * 2]);
    float self = di * di;
    float ax = h.x * self, ay = h.y * self;
    int e0 = rowptr[wid], e1 = rowptr[wid + 1];
    for (int e = e0; e < e1; e++) {
        int s = csr[e];
        float w = dis[s] * di;
        float2 hs = *reinterpret_cast<const float2*>(&x[(size_t)s * FIN + lane * 2]);
        ax += hs.x * w; ay += hs.y * w;
    }
    float2 o; o.x = ax; o.y = ay;
    *reinterpret_cast<float2*>(&xa[(size_t)wid * FIN + lane * 2]) = o;
}

// wave per node: r_rel = h . w_rel, r_root = h . w_root (stage 1)
__global__ __launch_bounds__(256) void k_dots(const float* __restrict__ h,
                                              const float* __restrict__ w_rel,
                                              const float* __restrict__ w_root,
                                              float* __restrict__ r_rel,
                                              float* __restrict__ r_root) {
    int wid = (blockIdx.x * blockDim.x + threadIdx.x) >> 6;
    int lane = threadIdx.x & 63;
    if (wid >= NN) return;
    float4 hv = *reinterpret_cast<const float4*>(&h[(size_t)wid * HDIM + lane * 4]);
    float4 wr = *reinterpret_cast<const float4*>(&w_rel[lane * 4]);
    float4 wo = *reinterpret_cast<const float4*>(&w_root[lane * 4]);
    float s1 = hv.x * wr.x + hv.y * wr.y + hv.z * wr.z + hv.w * wr.w;
    float s2 = hv.x * wo.x + hv.y * wo.y + hv.z * wo.z + hv.w * wo.w;
    for (int off = 32; off > 0; off >>= 1) {
        s1 += __shfl_down(s1, off);
        s2 += __shfl_down(s2, off);
    }
    if (lane == 0) { r_rel[wid] = s1; r_root[wid] = s2; }
}

// stages 2/3: wave per ACTIVE node, gather on hW, fused bias+relu+score dots
__global__ __launch_bounds__(256) void k_gcn_agg(const float* __restrict__ hW,
                                                 const float* __restrict__ dis,
                                                 const int* __restrict__ rowptr,
                                                 const int* __restrict__ csr,
                                                 const float* __restrict__ bias,
                                                 const int* __restrict__ list, int bpg,
                                                 const float* __restrict__ w_rel,
                                                 const float* __restrict__ w_root,
                                                 float* __restrict__ out,
                                                 float* __restrict__ r_rel,
                                                 float* __restrict__ r_root) {
    int blk = swz_block(blockIdx.x, bpg);
    int idx = blk * 4 + (threadIdx.x >> 6);
    int lane = threadIdx.x & 63;
    int wid = list[idx];
    float di = dis[wid];
    float4 h = *reinterpret_cast<const float4*>(&hW[(size_t)wid * HDIM + lane * 4]);
    float self = di * di;
    float ax = h.x * self, ay = h.y * self, az = h.z * self, aw = h.w * self;
    if (di > 0.f) {
        int e0 = rowptr[wid], e1 = rowptr[wid + 1];
        for (int e = e0; e < e1; e++) {
            int s = csr[e];
            float ds = dis[s];
            if (ds > 0.f) {
                float w = ds * di;
                float4 hs = *reinterpret_cast<const float4*>(&hW[(size_t)s * HDIM + lane * 4]);
                ax += hs.x * w; ay += hs.y * w; az += hs.z * w; aw += hs.w * w;
            }
        }
    }
    float4 b = *reinterpret_cast<const float4*>(&bias[lane * 4]);
    float4 o;
    o.x = fmaxf(ax + b.x, 0.f);
    o.y = fmaxf(ay + b.y, 0.f);
    o.z = fmaxf(az + b.z, 0.f);
    o.w = fmaxf(aw + b.w, 0.f);
    *reinterpret_cast<float4*>(&out[(size_t)wid * HDIM + lane * 4]) = o;
    float4 wr = *reinterpret_cast<const float4*>(&w_rel[lane * 4]);
    float4 wo = *reinterpret_cast<const float4*>(&w_root[lane * 4]);
    float s1 = o.x * wr.x + o.y * wr.y + o.z * wr.z + o.w * wr.w;
    float s2 = o.x * wo.x + o.y * wo.y + o.z * wo.z + o.w * wo.w;
    for (int off = 32; off > 0; off >>= 1) {
        s1 += __shfl_down(s1, off);
        s2 += __shfl_down(s2, off);
    }
    if (lane == 0) { r_rel[wid] = s1; r_root[wid] = s2; }
}

__global__ void k_score(const float* __restrict__ nmask, const int* __restrict__ rowptr,
                        const int* __restrict__ csr, const float* __restrict__ r_rel,
                        const float* __restrict__ r_root, const float* __restrict__ b_rel,
                        float* __restrict__ score) {
    int i = blockIdx.x * blockDim.x + threadIdx.x;
    if (i >= NN) return;
    if (nmask[i] <= 0.f) { score[i] = -INFINITY; return; }
    float s = b_rel[0] + r_root[i];
    int e0 = rowptr[i], e1 = rowptr[i + 1];
    for (int e = e0; e < e1; e++) {
        int src = csr[e];
        if (nmask[src] > 0.f) s += r_rel[src];
    }
    score[i] = s;
}

// block per graph: stable top-k via rank counting; writes new nmask
__global__ __launch_bounds__(256) void k_topk(const float* __restrict__ score, int k,
                                              float* __restrict__ nmask) {
    __shared__ float sc[NPG];
    int g = blockIdx.x, tid = threadIdx.x;
    float my = score[g * NPG + tid];
    sc[tid] = my;
    __syncthreads();
    int cnt = 0;
    for (int j = 0; j < NPG; j++) {
        float v = sc[j];
        cnt += (v > my || (v == my && j < tid)) ? 1 : 0;
    }
    nmask[g * NPG + tid] = (cnt < k) ? 1.0f : 0.0f;
}

// block per graph: deterministic active-node list (ascending node index)
__global__ __launch_bounds__(256) void k_build_list(const float* __restrict__ nmask, int k,
                                                    int* __restrict__ list) {
    __shared__ int pref[NPG];
    int g = blockIdx.x, tid = threadIdx.x;
    int a = (nmask[g * NPG + tid] > 0.f) ? 1 : 0;
    pref[tid] = a;
    __syncthreads();
    for (int off = 1; off < NPG; off <<= 1) {
        int v = (tid >= off) ? pref[tid - off] : 0;
        __syncthreads();
        pref[tid] += v;
        __syncthreads();
    }
    if (a) list[g * k + pref[tid] - 1] = g * NPG + tid;
}

// block per graph: fused x *= tanh(score)*mask (active rows only) + readout accumulate
__global__ __launch_bounds__(256) void k_poolout(float* __restrict__ h,
                                                 const float* __restrict__ score,
                                                 const float* __restrict__ nmask, float invk,
                                                 float* __restrict__ z) {
    __shared__ float tv[NPG];
    int g = blockIdx.x, f = threadIdx.x;
    {
        int node = g * NPG + f;
        tv[f] = (nmask[node] > 0.f) ? tanhf(score[node]) : 0.f;
    }
    __syncthreads();
    float s = 0.f, mx = -INFINITY;
    for (int n = 0; n < NPG; n++) {
        float t = tv[n];
        if (t != 0.f || nmask[g * NPG + n] > 0.f) {
            size_t p = (size_t)(g * NPG + n) * HDIM + f;
            float v = h[p] * t;
            h[p] = v;
            s += v;
            mx = fmaxf(mx, v);
        }
    }
    z[g * 768 + f] += s * invk;
    z[g * 768 + 256 + f] += mx;
    z[g * 768 + 512 + f] += s;
}

// ---------------- final MLP + log_softmax, block per graph ----------------
__global__ __launch_bounds__(256) void k_mlp(const float* __restrict__ z,
                                             const float* __restrict__ W1, const float* __restrict__ b1,
                                             const float* __restrict__ W2, const float* __restrict__ b2,
                                             const float* __restrict__ W3, const float* __restrict__ b3,
                                             float* __restrict__ out) {
    __shared__ float zb[768];
    __shared__ float t1[256];
    __shared__ float t2[128];
    __shared__ float t3[10];
    __shared__ float lse;
    int g = blockIdx.x, tid = threadIdx.x;
    zb[tid] = z[g * 768 + tid];
    zb[tid + 256] = z[g * 768 + 256 + tid];
    zb[tid + 512] = z[g * 768 + 512 + tid];
    __syncthreads();
    {
        float s = b1[tid];
        for (int i = 0; i < 768; i++) s += zb[i] * W1[(size_t)i * 256 + tid];
        t1[tid] = fmaxf(s, 0.f);
    }
    __syncthreads();
    if (tid < 128) {
        float s = b2[tid];
        for (int i = 0; i < 256; i++) s += t1[i] * W2[(size_t)i * 128 + tid];
        t2[tid] = fmaxf(s, 0.f);
    }
    __syncthreads();
    if (tid < 10) {
        float s = b3[tid];
        for (int i = 0; i < 128; i++) s += t2[i] * W3[(size_t)i * 10 + tid];
        t3[tid] = s;
    }
    __syncthreads();
    if (tid == 0) {
        float m = t3[0];
        for (int c = 1; c < 10; c++) m = fmaxf(m, t3[c]);
        float se = 0.f;
        for (int c = 0; c < 10; c++) se += expf(t3[c] - m);
        lse = m + logf(se);
    }
    __syncthreads();
    if (tid < 10) out[g * 10 + tid] = t3[tid] - lse;
}

// ---------------- launcher ----------------
extern "C" void kernel_launch(void* const* d_in, const int* in_sizes, int n_in,
                              void* d_out, int out_size, void* d_ws, size_t ws_size,
                              hipStream_t stream) {
    const float* x        = (const float*)d_in[0];
    const int*   ei       = (const int*)d_in[1];
    const float* conv1_W  = (const float*)d_in[3];
    const float* conv1_b  = (const float*)d_in[4];
    const float* conv2_W  = (const float*)d_in[5];
    const float* conv2_b  = (const float*)d_in[6];
    const float* conv3_W  = (const float*)d_in[7];
    const float* conv3_b  = (const float*)d_in[8];
    const float* p1_relW  = (const float*)d_in[9];
    const float* p1_relb  = (const float*)d_in[10];
    const float* p1_rootW = (const float*)d_in[11];
    const float* p2_relW  = (const float*)d_in[12];
    const float* p2_relb  = (const float*)d_in[13];
    const float* p2_rootW = (const float*)d_in[14];
    const float* fc1_W    = (const float*)d_in[15];
    const float* fc1_b    = (const float*)d_in[16];
    const float* fc2_W    = (const float*)d_in[17];
    const float* fc2_b    = (const float*)d_in[18];
    const float* fc3_W    = (const float*)d_in[19];
    const float* fc3_b    = (const float*)d_in[20];
    float* out = (float*)d_out;

    const int E = in_sizes[1] / 2;
    const int* e_src = ei;
    const int* e_dst = ei + E;

    // workspace layout
    char* base = (char*)d_ws;
    size_t off = 0;
    auto alloc = [&](size_t bytes) { size_t o = off; off = (off + bytes + 255) & ~(size_t)255; return o; };
    float* hW     = (float*)(base + alloc((size_t)NN * HDIM * 4));   // also used as xa (NN x FIN)
    float* hcur   = (float*)(base + alloc((size_t)NN * HDIM * 4));
    float* dis    = (float*)(base + alloc(NN * 4));
    float* r_rel  = (float*)(base + alloc(NN * 4));
    float* r_root = (float*)(base + alloc(NN * 4));
    float* score  = (float*)(base + alloc(NN * 4));
    float* nmask  = (float*)(base + alloc(NN * 4));
    int*   rowptr = (int*)(base + alloc((NN + 1) * 4));
    int*   counts = (int*)(base + alloc(NN * 4));
    int*   cursor = (int*)(base + alloc(NN * 4));
    int*   csr    = (int*)(base + alloc((size_t)E * 4));
    float* z      = (float*)(base + alloc((size_t)NG * 768 * 4));
    int*   list1  = (int*)(base + alloc((size_t)NG * 128 * 4));
    int*   list2  = (int*)(base + alloc((size_t)NG * 64 * 4));

    hipMemsetAsync(counts, 0, NN * 4, stream);
    hipMemsetAsync(cursor, 0, NN * 4, stream);
    hipMemsetAsync(z, 0, (size_t)NG * 768 * 4, stream);

    // CSR build (canonical sorted-by-src order => deterministic)
    int eblocks = (E + 255) / 256;
    k_count<<<eblocks, 256, 0, stream>>>(e_dst, counts, E);
    k_scan<<<1, 1024, 0, stream>>>(counts, rowptr);
    k_fill<<<eblocks, 256, 0, stream>>>(e_src, e_dst, rowptr, cursor, csr, E);
    k_sortw<<<NN * 64 / 256, 256, 0, stream>>>(rowptr, csr);
    k_init_mask<<<NN / 256, 256, 0, stream>>>(nmask);

    const int nodeBlocks = NN / 256;
    float* xa = hW;   // alias: stage-1 aggregated input

    // ---- stage 1: aggregate x first (128-wide), then GEMM with fused bias+relu ----
    k_dis<<<nodeBlocks, 256, 0, stream>>>(nmask, rowptr, csr, dis);
    k_agg_x<<<NN / 4, 256, 0, stream>>>(x, dis, rowptr, csr, xa);
    {
        dim3 ggrid(HDIM / BN, NN / BM);
        k_sgemm<<<ggrid, 256, 0, stream>>>(xa, conv1_W, hcur, FIN, nullptr, conv1_b);
    }
    k_dots<<<NN * 64 / 256, 256, 0, stream>>>(hcur, p1_relW, p1_rootW, r_rel, r_root);
    k_score<<<nodeBlocks, 256, 0, stream>>>(nmask, rowptr, csr, r_rel, r_root, p1_relb, score);
    k_topk<<<NG, 256, 0, stream>>>(score, 128, nmask);
    k_build_list<<<NG, 256, 0, stream>>>(nmask, 128, list1);
    k_poolout<<<NG, 256, 0, stream>>>(hcur, score, nmask, 1.0f / 128.0f, z);

    // ---- stages 2 & 3 ----
    struct Stage {
        const float* W; const float* b;
        const float* wrel; const float* brel; const float* wroot;
        int kpool;
        const int* list; int nact;
        int* outlist;
    };
    Stage stages[2] = {
        { conv2_W, conv2_b, p2_relW, p2_relb, p2_rootW, 64, list1, 16384, list2 },
        { conv3_W, conv3_b, p2_relW, p2_relb, p2_rootW, 32, list2, 8192,  nullptr },
    };

    for (int t = 0; t < 2; t++) {
        Stage& st = stages[t];
        dim3 ggrid(HDIM / BN, st.nact / BM);
        k_sgemm<<<ggrid, 256, 0, stream>>>(hcur, st.W, hW, HDIM, st.list, nullptr);
        k_dis<<<nodeBlocks, 256, 0, stream>>>(nmask, rowptr, csr, dis);
        int bpg = st.nact / (NG * 4);
        k_gcn_agg<<<st.nact / 4, 256, 0, stream>>>(hW, dis, rowptr, csr, st.b,
                                                   st.list, bpg, st.wrel, st.wroot,
                                                   hcur, r_rel, r_root);
        k_score<<<nodeBlocks, 256, 0, stream>>>(nmask, rowptr, csr, r_rel, r_root, st.brel, score);
        k_topk<<<NG, 256, 0, stream>>>(score, st.kpool, nmask);
        if (st.outlist) k_build_list<<<NG, 256, 0, stream>>>(nmask, st.kpool, st.outlist);
        k_poolout<<<NG, 256, 0, stream>>>(hcur, score, nmask, 1.0f / (float)st.kpool, z);
    }

    k_mlp<<<NG, 256, 0, stream>>>(z, fc1_W, fc1_b, fc2_W, fc2_b, fc3_W, fc3_b, out);
}

// Round 4
// 387.829 us; speedup vs baseline: 1.7303x; 1.2103x over previous
//
#include <hip/hip_runtime.h>
#include <math.h>

#define NG 128          // graphs
#define NPG 256         // nodes per graph
#define NN 32768        // total nodes
#define HDIM 256        // hidden
#define FIN 128         // input features

// ---------------- CSR build ----------------
__global__ void k_count(const int* __restrict__ dst, int* __restrict__ counts, int E) {
    int e = blockIdx.x * blockDim.x + threadIdx.x;
    if (e < E) atomicAdd(&counts[dst[e]], 1);
}

__global__ void k_scan(const int* __restrict__ counts, int* __restrict__ rowptr) {
    __shared__ int sums[1024];
    int tid = threadIdx.x;
    int base = tid * 32;
    int local[32];
    int s = 0;
#pragma unroll
    for (int j = 0; j < 32; j++) { local[j] = s; s += counts[base + j]; }
    sums[tid] = s;
    __syncthreads();
    for (int off = 1; off < 1024; off <<= 1) {
        int v = (tid >= off) ? sums[tid - off] : 0;
        __syncthreads();
        sums[tid] += v;
        __syncthreads();
    }
    int prev = (tid > 0) ? sums[tid - 1] : 0;
#pragma unroll
    for (int j = 0; j < 32; j++) rowptr[base + j] = prev + local[j];
    if (tid == 1023) rowptr[NN] = sums[1023];
}

__global__ void k_fill(const int* __restrict__ src, const int* __restrict__ dst,
                       const int* __restrict__ rowptr, int* __restrict__ cursor,
                       int* __restrict__ csr_src, int E) {
    int e = blockIdx.x * blockDim.x + threadIdx.x;
    if (e < E) {
        int d = dst[e];
        int p = atomicAdd(&cursor[d], 1);
        csr_src[rowptr[d] + p] = src[e];
    }
}

// deterministic canonical order: wave-parallel rank sort of each node's segment by src value
__global__ __launch_bounds__(256) void k_sortw(const int* __restrict__ rowptr, int* __restrict__ csr) {
    int wid = (blockIdx.x * blockDim.x + threadIdx.x) >> 6;
    int lane = threadIdx.x & 63;
    if (wid >= NN) return;
    int e0 = rowptr[wid];
    int d = rowptr[wid + 1] - e0;
    if (d <= 1) return;
    if (d <= 64) {
        int key = (lane < d) ? csr[e0 + lane] : 0x7fffffff;
        int rank = 0;
        for (int j = 0; j < d; j++) {
            int kj = __shfl(key, j);
            rank += (kj < key || (kj == key && j < lane)) ? 1 : 0;
        }
        if (lane < d) csr[e0 + rank] = key;
    } else if (lane == 0) {
        for (int a = e0 + 1; a < e0 + d; a++) {
            int key = csr[a];
            int b = a - 1;
            while (b >= e0 && csr[b] > key) { csr[b + 1] = csr[b]; b--; }
            csr[b + 1] = key;
        }
    }
}

__global__ void k_init_mask(float* __restrict__ nmask) {
    int i = blockIdx.x * blockDim.x + threadIdx.x;
    if (i < NN) nmask[i] = 1.0f;
}

// ---------------- SGEMM: C[list[m] x 256] = A[list[m] x K] @ B[K x 256], f32 ----------------
#define BM 64
#define BN 64
#define BK 16
__global__ __launch_bounds__(256) void k_sgemm(const float* __restrict__ A,
                                               const float* __restrict__ B,
                                               float* __restrict__ C, int K,
                                               const int* __restrict__ list,
                                               const float* __restrict__ brelu) {
    const int N = HDIM;
    __shared__ float As[BK][BM];
    __shared__ float Bs[BK][BN];
    int tid = threadIdx.x;
    int tx = tid & 15, ty = tid >> 4;
    int row0 = blockIdx.y * BM, col0 = blockIdx.x * BN;
    int lm = tid >> 2;
    int arow = list ? list[row0 + lm] : (row0 + lm);
    int crow[4];
#pragma unroll
    for (int i = 0; i < 4; i++) {
        int r = row0 + ty * 4 + i;
        crow[i] = list ? list[r] : r;
    }
    float acc[4][4] = {};
    for (int kb = 0; kb < K; kb += BK) {
        {
            int k = (tid & 3) * 4;
            float4 av = *reinterpret_cast<const float4*>(&A[(size_t)arow * K + kb + k]);
            As[k + 0][lm] = av.x; As[k + 1][lm] = av.y; As[k + 2][lm] = av.z; As[k + 3][lm] = av.w;
        }
        {
            int l = tid * 4;
            int k = l >> 6, c = l & 63;
            *reinterpret_cast<float4*>(&Bs[k][c]) =
                *reinterpret_cast<const float4*>(&B[(size_t)(kb + k) * N + col0 + c]);
        }
        __syncthreads();
#pragma unroll
        for (int k = 0; k < BK; k++) {
            float4 a = *reinterpret_cast<float4*>(&As[k][ty * 4]);
            float4 b = *reinterpret_cast<float4*>(&Bs[k][tx * 4]);
            float av[4] = {a.x, a.y, a.z, a.w};
            float bv[4] = {b.x, b.y, b.z, b.w};
#pragma unroll
            for (int i = 0; i < 4; i++)
#pragma unroll
                for (int j = 0; j < 4; j++) acc[i][j] += av[i] * bv[j];
        }
        __syncthreads();
    }
    float4 bb = make_float4(0.f, 0.f, 0.f, 0.f);
    if (brelu) bb = *reinterpret_cast<const float4*>(&brelu[col0 + tx * 4]);
#pragma unroll
    for (int i = 0; i < 4; i++) {
        float4 v = make_float4(acc[i][0], acc[i][1], acc[i][2], acc[i][3]);
        if (brelu) {
            v.x = fmaxf(v.x + bb.x, 0.f);
            v.y = fmaxf(v.y + bb.y, 0.f);
            v.z = fmaxf(v.z + bb.z, 0.f);
            v.w = fmaxf(v.w + bb.w, 0.f);
        }
        *reinterpret_cast<float4*>(&C[(size_t)crow[i] * N + col0 + tx * 4]) = v;
    }
}

// ---------------- per-stage kernels ----------------
__global__ void k_dis(const float* __restrict__ nmask, const int* __restrict__ rowptr,
                      const int* __restrict__ csr, float* __restrict__ dis) {
    int i = blockIdx.x * blockDim.x + threadIdx.x;
    if (i >= NN) return;
    if (nmask[i] <= 0.f) { dis[i] = 0.f; return; }
    int e0 = rowptr[i], e1 = rowptr[i + 1];
    int cnt = 1;
    for (int e = e0; e < e1; e++) cnt += (nmask[csr[e]] > 0.f) ? 1 : 0;
    dis[i] = rsqrtf((float)cnt);
}

// XCD-locality swizzle
__device__ __forceinline__ int swz_block(int bid, int bpg) {
    int xcd = bid & 7, r = bid >> 3;
    int graph = xcd * (NG / 8) + r / bpg;
    int sub = r - (r / bpg) * bpg;
    return graph * bpg + sub;
}

// stage 1 only: xa = D^{-1/2}(A+I)D^{-1/2} x  (x is FIN wide)
__global__ __launch_bounds__(256) void k_agg_x(const float* __restrict__ x,
                                               const float* __restrict__ dis,
                                               const int* __restrict__ rowptr,
                                               const int* __restrict__ csr,
                                               float* __restrict__ xa) {
    int blk = swz_block(blockIdx.x, NN / (NG * 4));
    int wid = blk * 4 + (threadIdx.x >> 6);
    int lane = threadIdx.x & 63;
    float di = dis[wid];
    float2 h = *reinterpret_cast<const float2*>(&x[(size_t)wid * FIN + lane * 2]);
    float self = di * di;
    float ax = h.x * self, ay = h.y * self;
    int e0 = rowptr[wid], e1 = rowptr[wid + 1];
    for (int e = e0; e < e1; e++) {
        int s = csr[e];
        float w = dis[s] * di;
        float2 hs = *reinterpret_cast<const float2*>(&x[(size_t)s * FIN + lane * 2]);
        ax += hs.x * w; ay += hs.y * w;
    }
    float2 o; o.x = ax; o.y = ay;
    *reinterpret_cast<float2*>(&xa[(size_t)wid * FIN + lane * 2]) = o;
}

// wave per node: r_rel = h . w_rel, r_root = h . w_root (stage 1)
__global__ __launch_bounds__(256) void k_dots(const float* __restrict__ h,
                                              const float* __restrict__ w_rel,
                                              const float* __restrict__ w_root,
                                              float* __restrict__ r_rel,
                                              float* __restrict__ r_root) {
    int wid = (blockIdx.x * blockDim.x + threadIdx.x) >> 6;
    int lane = threadIdx.x & 63;
    if (wid >= NN) return;
    float4 hv = *reinterpret_cast<const float4*>(&h[(size_t)wid * HDIM + lane * 4]);
    float4 wr = *reinterpret_cast<const float4*>(&w_rel[lane * 4]);
    float4 wo = *reinterpret_cast<const float4*>(&w_root[lane * 4]);
    float s1 = hv.x * wr.x + hv.y * wr.y + hv.z * wr.z + hv.w * wr.w;
    float s2 = hv.x * wo.x + hv.y * wo.y + hv.z * wo.z + hv.w * wo.w;
    for (int off = 32; off > 0; off >>= 1) {
        s1 += __shfl_down(s1, off);
        s2 += __shfl_down(s2, off);
    }
    if (lane == 0) { r_rel[wid] = s1; r_root[wid] = s2; }
}

// stages 2/3: wave per ACTIVE node, gather on hW, fused bias+relu+score dots
__global__ __launch_bounds__(256) void k_gcn_agg(const float* __restrict__ hW,
                                                 const float* __restrict__ dis,
                                                 const int* __restrict__ rowptr,
                                                 const int* __restrict__ csr,
                                                 const float* __restrict__ bias,
                                                 const int* __restrict__ list, int bpg,
                                                 const float* __restrict__ w_rel,
                                                 const float* __restrict__ w_root,
                                                 float* __restrict__ out,
                                                 float* __restrict__ r_rel,
                                                 float* __restrict__ r_root) {
    int blk = swz_block(blockIdx.x, bpg);
    int idx = blk * 4 + (threadIdx.x >> 6);
    int lane = threadIdx.x & 63;
    int wid = list[idx];
    float di = dis[wid];
    float4 h = *reinterpret_cast<const float4*>(&hW[(size_t)wid * HDIM + lane * 4]);
    float self = di * di;
    float ax = h.x * self, ay = h.y * self, az = h.z * self, aw = h.w * self;
    if (di > 0.f) {
        int e0 = rowptr[wid], e1 = rowptr[wid + 1];
        for (int e = e0; e < e1; e++) {
            int s = csr[e];
            float ds = dis[s];
            if (ds > 0.f) {
                float w = ds * di;
                float4 hs = *reinterpret_cast<const float4*>(&hW[(size_t)s * HDIM + lane * 4]);
                ax += hs.x * w; ay += hs.y * w; az += hs.z * w; aw += hs.w * w;
            }
        }
    }
    float4 b = *reinterpret_cast<const float4*>(&bias[lane * 4]);
    float4 o;
    o.x = fmaxf(ax + b.x, 0.f);
    o.y = fmaxf(ay + b.y, 0.f);
    o.z = fmaxf(az + b.z, 0.f);
    o.w = fmaxf(aw + b.w, 0.f);
    *reinterpret_cast<float4*>(&out[(size_t)wid * HDIM + lane * 4]) = o;
    float4 wr = *reinterpret_cast<const float4*>(&w_rel[lane * 4]);
    float4 wo = *reinterpret_cast<const float4*>(&w_root[lane * 4]);
    float s1 = o.x * wr.x + o.y * wr.y + o.z * wr.z + o.w * wr.w;
    float s2 = o.x * wo.x + o.y * wo.y + o.z * wo.z + o.w * wo.w;
    for (int off = 32; off > 0; off >>= 1) {
        s1 += __shfl_down(s1, off);
        s2 += __shfl_down(s2, off);
    }
    if (lane == 0) { r_rel[wid] = s1; r_root[wid] = s2; }
}

__global__ void k_score(const float* __restrict__ nmask, const int* __restrict__ rowptr,
                        const int* __restrict__ csr, const float* __restrict__ r_rel,
                        const float* __restrict__ r_root, const float* __restrict__ b_rel,
                        float* __restrict__ score) {
    int i = blockIdx.x * blockDim.x + threadIdx.x;
    if (i >= NN) return;
    if (nmask[i] <= 0.f) { score[i] = -INFINITY; return; }
    float s = b_rel[0] + r_root[i];
    int e0 = rowptr[i], e1 = rowptr[i + 1];
    for (int e = e0; e < e1; e++) {
        int src = csr[e];
        if (nmask[src] > 0.f) s += r_rel[src];
    }
    score[i] = s;
}

// block per graph: stable top-k (rank counting) -> nmask + deterministic active list
__global__ __launch_bounds__(256) void k_topk(const float* __restrict__ score, int k,
                                              float* __restrict__ nmask,
                                              int* __restrict__ list) {
    __shared__ float sc[NPG];
    __shared__ int pref[NPG];
    int g = blockIdx.x, tid = threadIdx.x;
    float my = score[g * NPG + tid];
    sc[tid] = my;
    __syncthreads();
    int cnt = 0;
    for (int j = 0; j < NPG; j++) {
        float v = sc[j];
        cnt += (v > my || (v == my && j < tid)) ? 1 : 0;
    }
    int a = (cnt < k) ? 1 : 0;
    nmask[g * NPG + tid] = (float)a;
    pref[tid] = a;
    __syncthreads();
    for (int off = 1; off < NPG; off <<= 1) {
        int v = (tid >= off) ? pref[tid - off] : 0;
        __syncthreads();
        pref[tid] += v;
        __syncthreads();
    }
    if (a) list[g * k + pref[tid] - 1] = g * NPG + tid;
}

// grid = NG*4: block = (graph, 64-feature chunk); 256 thr = 64 feat x 4 node-partitions
__global__ __launch_bounds__(256) void k_poolout2(float* __restrict__ h,
                                                  const float* __restrict__ score,
                                                  const int* __restrict__ list, int k,
                                                  float invk, float* __restrict__ z) {
    __shared__ float tv[128];        // k <= 128
    __shared__ float red_s[4][64];
    __shared__ float red_m[4][64];
    int g = blockIdx.x >> 2, fc = blockIdx.x & 3;
    int tid = threadIdx.x;
    int x = tid & 63, y = tid >> 6;
    if (tid < k) tv[tid] = tanhf(score[list[g * k + tid]]);
    __syncthreads();
    int f = fc * 64 + x;
    float s = 0.f, mx = -INFINITY;
    for (int idx = y; idx < k; idx += 4) {
        int node = list[g * k + idx];
        size_t p = (size_t)node * HDIM + f;
        float v = h[p] * tv[idx];
        h[p] = v;
        s += v;
        mx = fmaxf(mx, v);
    }
    red_s[y][x] = s;
    red_m[y][x] = mx;
    __syncthreads();
    if (y == 0) {
        s = red_s[0][x] + red_s[1][x] + red_s[2][x] + red_s[3][x];
        mx = fmaxf(fmaxf(red_m[0][x], red_m[1][x]), fmaxf(red_m[2][x], red_m[3][x]));
        z[g * 768 + f] += s * invk;
        z[g * 768 + 256 + f] += mx;
        z[g * 768 + 512 + f] += s;
    }
}

// ---------------- final MLP + log_softmax, block per graph ----------------
__global__ __launch_bounds__(256) void k_mlp(const float* __restrict__ z,
                                             const float* __restrict__ W1, const float* __restrict__ b1,
                                             const float* __restrict__ W2, const float* __restrict__ b2,
                                             const float* __restrict__ W3, const float* __restrict__ b3,
                                             float* __restrict__ out) {
    __shared__ float zb[768];
    __shared__ float t1[256];
    __shared__ float t2[128];
    __shared__ float t3[10];
    __shared__ float lse;
    int g = blockIdx.x, tid = threadIdx.x;
    zb[tid] = z[g * 768 + tid];
    zb[tid + 256] = z[g * 768 + 256 + tid];
    zb[tid + 512] = z[g * 768 + 512 + tid];
    __syncthreads();
    {
        float s = b1[tid];
        for (int i = 0; i < 768; i++) s += zb[i] * W1[(size_t)i * 256 + tid];
        t1[tid] = fmaxf(s, 0.f);
    }
    __syncthreads();
    if (tid < 128) {
        float s = b2[tid];
        for (int i = 0; i < 256; i++) s += t1[i] * W2[(size_t)i * 128 + tid];
        t2[tid] = fmaxf(s, 0.f);
    }
    __syncthreads();
    if (tid < 10) {
        float s = b3[tid];
        for (int i = 0; i < 128; i++) s += t2[i] * W3[(size_t)i * 10 + tid];
        t3[tid] = s;
    }
    __syncthreads();
    if (tid == 0) {
        float m = t3[0];
        for (int c = 1; c < 10; c++) m = fmaxf(m, t3[c]);
        float se = 0.f;
        for (int c = 0; c < 10; c++) se += expf(t3[c] - m);
        lse = m + logf(se);
    }
    __syncthreads();
    if (tid < 10) out[g * 10 + tid] = t3[tid] - lse;
}

// ---------------- launcher ----------------
extern "C" void kernel_launch(void* const* d_in, const int* in_sizes, int n_in,
                              void* d_out, int out_size, void* d_ws, size_t ws_size,
                              hipStream_t stream) {
    const float* x        = (const float*)d_in[0];
    const int*   ei       = (const int*)d_in[1];
    const float* conv1_W  = (const float*)d_in[3];
    const float* conv1_b  = (const float*)d_in[4];
    const float* conv2_W  = (const float*)d_in[5];
    const float* conv2_b  = (const float*)d_in[6];
    const float* conv3_W  = (const float*)d_in[7];
    const float* conv3_b  = (const float*)d_in[8];
    const float* p1_relW  = (const float*)d_in[9];
    const float* p1_relb  = (const float*)d_in[10];
    const float* p1_rootW = (const float*)d_in[11];
    const float* p2_relW  = (const float*)d_in[12];
    const float* p2_relb  = (const float*)d_in[13];
    const float* p2_rootW = (const float*)d_in[14];
    const float* fc1_W    = (const float*)d_in[15];
    const float* fc1_b    = (const float*)d_in[16];
    const float* fc2_W    = (const float*)d_in[17];
    const float* fc2_b    = (const float*)d_in[18];
    const float* fc3_W    = (const float*)d_in[19];
    const float* fc3_b    = (const float*)d_in[20];
    float* out = (float*)d_out;

    const int E = in_sizes[1] / 2;
    const int* e_src = ei;
    const int* e_dst = ei + E;

    // workspace layout
    char* base = (char*)d_ws;
    size_t off = 0;
    auto alloc = [&](size_t bytes) { size_t o = off; off = (off + bytes + 255) & ~(size_t)255; return o; };
    float* hW     = (float*)(base + alloc((size_t)NN * HDIM * 4));   // also used as xa
    float* hcur   = (float*)(base + alloc((size_t)NN * HDIM * 4));
    float* dis    = (float*)(base + alloc(NN * 4));
    float* r_rel  = (float*)(base + alloc(NN * 4));
    float* r_root = (float*)(base + alloc(NN * 4));
    float* score  = (float*)(base + alloc(NN * 4));
    float* nmask  = (float*)(base + alloc(NN * 4));
    int*   rowptr = (int*)(base + alloc((NN + 1) * 4));
    int*   counts = (int*)(base + alloc(NN * 4));
    int*   cursor = (int*)(base + alloc(NN * 4));
    int*   csr    = (int*)(base + alloc((size_t)E * 4));
    float* z      = (float*)(base + alloc((size_t)NG * 768 * 4));
    int*   list1  = (int*)(base + alloc((size_t)NG * 128 * 4));
    int*   list2  = (int*)(base + alloc((size_t)NG * 64 * 4));
    int*   list3  = (int*)(base + alloc((size_t)NG * 32 * 4));

    hipMemsetAsync(counts, 0, NN * 4, stream);
    hipMemsetAsync(cursor, 0, NN * 4, stream);
    hipMemsetAsync(z, 0, (size_t)NG * 768 * 4, stream);

    // CSR build
    int eblocks = (E + 255) / 256;
    k_count<<<eblocks, 256, 0, stream>>>(e_dst, counts, E);
    k_scan<<<1, 1024, 0, stream>>>(counts, rowptr);
    k_fill<<<eblocks, 256, 0, stream>>>(e_src, e_dst, rowptr, cursor, csr, E);
    k_sortw<<<NN * 64 / 256, 256, 0, stream>>>(rowptr, csr);
    k_init_mask<<<NN / 256, 256, 0, stream>>>(nmask);

    const int nodeBlocks = NN / 256;
    float* xa = hW;

    // ---- stage 1 ----
    k_dis<<<nodeBlocks, 256, 0, stream>>>(nmask, rowptr, csr, dis);
    k_agg_x<<<NN / 4, 256, 0, stream>>>(x, dis, rowptr, csr, xa);
    {
        dim3 ggrid(HDIM / BN, NN / BM);
        k_sgemm<<<ggrid, 256, 0, stream>>>(xa, conv1_W, hcur, FIN, nullptr, conv1_b);
    }
    k_dots<<<NN * 64 / 256, 256, 0, stream>>>(hcur, p1_relW, p1_rootW, r_rel, r_root);
    k_score<<<nodeBlocks, 256, 0, stream>>>(nmask, rowptr, csr, r_rel, r_root, p1_relb, score);
    k_topk<<<NG, 256, 0, stream>>>(score, 128, nmask, list1);
    k_poolout2<<<NG * 4, 256, 0, stream>>>(hcur, score, list1, 128, 1.0f / 128.0f, z);

    // ---- stages 2 & 3 ----
    struct Stage {
        const float* W; const float* b;
        const float* wrel; const float* brel; const float* wroot;
        int kpool;
        const int* list; int nact;
        int* outlist;
    };
    Stage stages[2] = {
        { conv2_W, conv2_b, p2_relW, p2_relb, p2_rootW, 64, list1, 16384, list2 },
        { conv3_W, conv3_b, p2_relW, p2_relb, p2_rootW, 32, list2, 8192,  list3 },
    };

    for (int t = 0; t < 2; t++) {
        Stage& st = stages[t];
        dim3 ggrid(HDIM / BN, st.nact / BM);
        k_sgemm<<<ggrid, 256, 0, stream>>>(hcur, st.W, hW, HDIM, st.list, nullptr);
        k_dis<<<nodeBlocks, 256, 0, stream>>>(nmask, rowptr, csr, dis);
        int bpg = st.nact / (NG * 4);
        k_gcn_agg<<<st.nact / 4, 256, 0, stream>>>(hW, dis, rowptr, csr, st.b,
                                                   st.list, bpg, st.wrel, st.wroot,
                                                   hcur, r_rel, r_root);
        k_score<<<nodeBlocks, 256, 0, stream>>>(nmask, rowptr, csr, r_rel, r_root, st.brel, score);
        k_topk<<<NG, 256, 0, stream>>>(score, st.kpool, nmask, st.outlist);
        k_poolout2<<<NG * 4, 256, 0, stream>>>(hcur, score, st.outlist, st.kpool,
                                               1.0f / (float)st.kpool, z);
    }

    k_mlp<<<NG, 256, 0, stream>>>(z, fc1_W, fc1_b, fc2_W, fc2_b, fc3_W, fc3_b, out);
}